// Round 4
// baseline (374.740 us; speedup 1.0000x reference)
//
#include <hip/hip_runtime.h>
#include <math.h>

#define BB 8
#define NN 4096
#define CC 640
#define SS 77
#define XDIM 768
#define HH 8
#define DH 80
#define BETA 0.5f
#define TAU 0.1f
#define EPSV 1e-8f

typedef _Float16 half_t;
typedef _Float16 h8 __attribute__((ext_vector_type(8)));
typedef _Float16 h4 __attribute__((ext_vector_type(4)));
typedef float f4 __attribute__((ext_vector_type(4)));

// ---------------- block reduction helper (256 threads) ----------------
__device__ __forceinline__ float blk_reduce(float v, float* red, int tid) {
    red[tid] = v;
    __syncthreads();
#pragma unroll
    for (int st = 128; st > 0; st >>= 1) {
        if (tid < st) red[tid] += red[tid + st];
        __syncthreads();
    }
    float r = red[0];
    __syncthreads();
    return r;
}

// =======================================================================
// K1: all weight packing + erase_pre, merged. (unchanged from R3)
// =======================================================================
__global__ __launch_bounds__(256) void wpack_all(const float* __restrict__ Wk,
                                                 const float* __restrict__ Wv,
                                                 const float* __restrict__ Wq,
                                                 const float* __restrict__ Wo,
                                                 const float* __restrict__ target,
                                                 const float* __restrict__ anchor,
                                                 const float* __restrict__ pres,
                                                 half_t* __restrict__ pW,
                                                 half_t* __restrict__ pWq,
                                                 half_t* __restrict__ pWo,
                                                 float* __restrict__ u_hat,
                                                 float* __restrict__ wvec,
                                                 float* __restrict__ ginv) {
    __shared__ float red[256];
    int blk = blockIdx.x;
    int tid = threadIdx.x;
    if (blk < 480) {
        int idx = blk * 256 + tid;
        int l = idx & 63;
        int kb = (idx >> 6) % 24;
        int nt = idx / (24 * 64);
        int n = nt * 16 + (l & 15);
        int k0 = kb * 32 + ((l >> 4) << 3);
        half_t vals[8];
#pragma unroll
        for (int j = 0; j < 8; j++) {
            float w = (n < CC) ? Wk[(size_t)(k0 + j) * CC + n]
                               : Wv[(size_t)(k0 + j) * CC + (n - CC)];
            vals[j] = (half_t)w;
        }
        *(h8*)(pW + (size_t)idx * 8) = *(h8*)vals;
        return;
    }
    blk -= 480;
    if (blk < 240) {
        const float qs = 0.11180339887498949f;
        int idx = blk * 256 + tid;
        int l = idx & 63;
        int kb = (idx >> 6) % 3;
        int nt = (idx / (3 * 64)) % 40;
        int h = idx / (40 * 3 * 64);
        int n = nt * 16 + (l & 15);
        int k0 = kb * 32 + ((l >> 4) << 3);
        half_t vals[8];
#pragma unroll
        for (int j = 0; j < 8; j++) {
            int d = k0 + j;
            float w = (d < DH) ? qs * Wq[(size_t)n * CC + h * DH + d] : 0.f;
            vals[j] = (half_t)w;
        }
        *(h8*)(pWq + (size_t)idx * 8) = *(h8*)vals;
        return;
    }
    blk -= 240;
    if (blk < 240) {
        int idx = blk * 256 + tid;
        int l = idx & 63;
        int kb = (idx >> 6) % 3;
        int nt = (idx / (3 * 64)) % 40;
        int h = idx / (40 * 3 * 64);
        int n = nt * 16 + (l & 15);
        int k0 = kb * 32 + ((l >> 4) << 3);
        half_t vals[8];
#pragma unroll
        for (int j = 0; j < 8; j++) {
            int d = k0 + j;
            float w = (d < DH) ? Wo[(size_t)(h * DH + d) * CC + n] : 0.f;
            vals[j] = (half_t)w;
        }
        *(h8*)(pWo + (size_t)idx * 8) = *(h8*)vals;
        return;
    }
    blk -= 240;
    {
        int s = blk;
        const float* p0 = pres + (size_t)s * CC;
        const float* p1 = pres + (size_t)(SS + s) * CC;
        const float* tg = target + (size_t)s * CC;
        const float* an = anchor + (size_t)s * CC;
        float x0[3], x1[3], xt[3], xa[3];
        float a00 = 0, a01 = 0, a11 = 0, bt0 = 0, bt1 = 0, ba0 = 0, ba1 = 0;
#pragma unroll
        for (int i = 0; i < 3; i++) {
            int c = tid + i * 256;
            bool ok = c < CC;
            float v0 = ok ? p0[c] : 0.f;
            float v1 = ok ? p1[c] : 0.f;
            float t = ok ? tg[c] : 0.f;
            float a = ok ? an[c] : 0.f;
            x0[i] = v0; x1[i] = v1; xt[i] = t; xa[i] = a;
            a00 += v0 * v0; a01 += v0 * v1; a11 += v1 * v1;
            bt0 += v0 * t; bt1 += v1 * t; ba0 += v0 * a; ba1 += v1 * a;
        }
        a00 = blk_reduce(a00, red, tid); a01 = blk_reduce(a01, red, tid);
        a11 = blk_reduce(a11, red, tid);
        bt0 = blk_reduce(bt0, red, tid); bt1 = blk_reduce(bt1, red, tid);
        ba0 = blk_reduce(ba0, red, tid); ba1 = blk_reduce(ba1, red, tid);
        float det = a00 * a11 - a01 * a01;
        float i00 = a11 / det, i01 = -a01 / det, i11 = a00 / det;
        float ct0 = i00 * bt0 + i01 * bt1, ct1 = i01 * bt0 + i11 * bt1;
        float ca0 = i00 * ba0 + i01 * ba1, ca1 = i01 * ba0 + i11 * ba1;
        float ud[3], ad[3], at[3];
        float nu2 = 0, dua = 0;
#pragma unroll
        for (int i = 0; i < 3; i++) {
            ud[i] = xt[i] - ct0 * x0[i] - ct1 * x1[i];
            ad[i] = xa[i] - ca0 * x0[i] - ca1 * x1[i];
            nu2 += ud[i] * ud[i]; dua += ud[i] * ad[i];
        }
        nu2 = blk_reduce(nu2, red, tid); dua = blk_reduce(dua, red, tid);
        float nu = sqrtf(nu2) + EPSV;
        float f = dua / nu;
        float na2 = 0;
#pragma unroll
        for (int i = 0; i < 3; i++) {
            at[i] = ad[i] - f * (ud[i] / nu);
            na2 += at[i] * at[i];
        }
        na2 = blk_reduce(na2, red, tid);
        float nai = 1.f / (sqrtf(na2) + EPSV);
#pragma unroll
        for (int i = 0; i < 3; i++) {
            int c = tid + i * 256;
            if (c < CC) {
                float uh = ud[i] / nu;
                float ah = at[i] * nai;
                u_hat[(size_t)s * CC + c] = uh;
                wvec[(size_t)s * CC + c] = BETA * ah - uh;
            }
        }
        if (tid == 0) {
            ginv[s * 4 + 0] = i00; ginv[s * 4 + 1] = i01;
            ginv[s * 4 + 2] = i11; ginv[s * 4 + 3] = 0.f;
        }
    }
}

// =======================================================================
// K2: kv_gemm + fused CORA erase. grid 78: job = blk&1 (0: k-cols, 1: v-cols),
// rows (blk>>1)*16. 256 thr / 4 waves, 10 n-tiles per wave (640 cols per job).
// v-job applies the erase in-register before storing (one fewer kernel +
// no vmat read-modify-write round trip).
// =======================================================================
__global__ __launch_bounds__(256) void kv_gemm(const float* __restrict__ enc,
                                               const half_t* __restrict__ pW,
                                               const float* __restrict__ pres,
                                               const float* __restrict__ u_hat,
                                               const float* __restrict__ wvec,
                                               const float* __restrict__ ginv,
                                               float* __restrict__ kmat,
                                               float* __restrict__ vmat) {
    __shared__ half_t sA[16][776];
    __shared__ float red[16][4];
    __shared__ float tf[16];
    int blk = blockIdx.x;
    int job = blk & 1;
    int r0 = (blk >> 1) * 16;
    int tid = threadIdx.x;
    // stage enc rows (vectorized f4)
    for (int idx = tid; idx < 16 * 192; idx += 256) {
        int r = idx / 192, c4 = idx - r * 192;
        int bs = r0 + r;
        f4 v = (bs < BB * SS) ? *(const f4*)(enc + (size_t)bs * XDIM + c4 * 4)
                              : (f4){0.f, 0.f, 0.f, 0.f};
        h4 hv = {(half_t)v[0], (half_t)v[1], (half_t)v[2], (half_t)v[3]};
        *(h4*)&sA[r][c4 * 4] = hv;
    }
    if (tid < 64) ((float*)red)[tid] = 0.f;
    __syncthreads();
    int w = tid >> 6, l = tid & 63;
    int arow = l & 15, aq = l >> 4;
    f4 acc[10];
#pragma unroll
    for (int i = 0; i < 10; i++) acc[i] = (f4){0.f, 0.f, 0.f, 0.f};
    for (int kb = 0; kb < 24; kb++) {
        h8 af = *(const h8*)&sA[arow][kb * 32 + aq * 8];
#pragma unroll
        for (int nt = 0; nt < 10; nt++) {
            int ntile = job * 40 + w * 10 + nt;
            h8 bf = *(const h8*)(pW + ((size_t)(ntile * 24 + kb) * 64 + l) * 8);
            acc[nt] = __builtin_amdgcn_mfma_f32_16x16x32_f16(af, bf, acc[nt], 0, 0, 0);
        }
    }
    if (job == 0) {
#pragma unroll
        for (int nt = 0; nt < 10; nt++) {
            int col = (w * 10 + nt) * 16 + arow;
#pragma unroll
            for (int i = 0; i < 4; i++) {
                int bs = r0 + aq * 4 + i;
                if (bs < BB * SS) kmat[(size_t)bs * CC + col] = acc[nt][i];
            }
        }
        return;
    }
    // ---- erase: per-row dots (b0, b1, t, |v|^2) ----
    float part[4][4];
#pragma unroll
    for (int i = 0; i < 4; i++)
#pragma unroll
        for (int q = 0; q < 4; q++) part[i][q] = 0.f;
#pragma unroll
    for (int nt = 0; nt < 10; nt++) {
        int c = (w * 10 + nt) * 16 + arow;
#pragma unroll
        for (int i = 0; i < 4; i++) {
            int s = (r0 + aq * 4 + i) % SS;
            float vv = acc[nt][i];
            float P0 = pres[(size_t)s * CC + c];
            float P1 = pres[(size_t)(SS + s) * CC + c];
            float UH = u_hat[(size_t)s * CC + c];
            part[i][0] += P0 * vv; part[i][1] += P1 * vv;
            part[i][2] += UH * vv; part[i][3] += vv * vv;
        }
    }
#pragma unroll
    for (int st = 1; st < 16; st <<= 1)
#pragma unroll
        for (int i = 0; i < 4; i++)
#pragma unroll
            for (int q = 0; q < 4; q++)
                part[i][q] += __shfl_xor(part[i][q], st, 64);
    if (arow == 0) {
#pragma unroll
        for (int i = 0; i < 4; i++)
#pragma unroll
            for (int q = 0; q < 4; q++)
                atomicAdd(&red[aq * 4 + i][q], part[i][q]);
    }
    __syncthreads();
    if (tid < 16) {
        int s = (r0 + tid) % SS;
        float b0 = red[tid][0], b1 = red[tid][1], tt = red[tid][2], n2 = red[tid][3];
        float i00 = ginv[s * 4], i01 = ginv[s * 4 + 1], i11 = ginv[s * 4 + 2];
        float pv2 = b0 * (i00 * b0 + i01 * b1) + b1 * (i01 * b0 + i11 * b1);
        float vf2 = fmaxf(n2 - pv2, 0.f);
        float denom = sqrtf(vf2) + EPSV;
        bool keep = (fabsf(tt) / denom) < TAU;
        tf[tid] = keep ? 0.f : tt;
    }
    __syncthreads();
#pragma unroll
    for (int nt = 0; nt < 10; nt++) {
        int c = (w * 10 + nt) * 16 + arow;
#pragma unroll
        for (int i = 0; i < 4; i++) {
            int bs = r0 + aq * 4 + i;
            if (bs < BB * SS) {
                int s = bs % SS;
                float val = acc[nt][i] + tf[aq * 4 + i] * wvec[(size_t)s * CC + c];
                vmat[(size_t)bs * CC + c] = val;
            }
        }
    }
}

// =======================================================================
// K3: hsgemm — per (b,h): C[80,640] = X[80,80] @ W_h[80,640] via MFMA,
// scatter fp16 into attn B-frag streams pM / pV (score coord = h*80+s,
// pad s in [77,80) written 0). (unchanged from R3)
// =======================================================================
__global__ __launch_bounds__(512) void hsgemm(const float* __restrict__ kmat,
                                              const float* __restrict__ vmat,
                                              const half_t* __restrict__ pWq,
                                              const half_t* __restrict__ pWo,
                                              half_t* __restrict__ pM,
                                              half_t* __restrict__ pV) {
    __shared__ half_t sX[80][104];
    int blk = blockIdx.x;
    int b = blk & 7;
    int h = (blk >> 3) & 7;
    int job = blk >> 6;
    const float* src = job ? vmat : kmat;
    const half_t* pWx = job ? pWo : pWq;
    int tid = threadIdx.x;
    for (int e = tid; e < 80 * 104; e += 512) {
        int r = e / 104, d = e - r * 104;
        float v = 0.f;
        if (r < SS && d < DH) v = src[((size_t)b * SS + r) * CC + h * DH + d];
        sX[r][d] = (half_t)v;
    }
    __syncthreads();
    int w = tid >> 6, l = tid & 63;
    int arow = l & 15, aq = l >> 4;
    f4 acc[5][5];
#pragma unroll
    for (int mt = 0; mt < 5; mt++)
#pragma unroll
        for (int nn = 0; nn < 5; nn++) acc[mt][nn] = (f4){0.f, 0.f, 0.f, 0.f};
#pragma unroll
    for (int kb = 0; kb < 3; kb++) {
        h8 af[5];
#pragma unroll
        for (int mt = 0; mt < 5; mt++)
            af[mt] = *(const h8*)&sX[mt * 16 + arow][kb * 32 + aq * 8];
#pragma unroll
        for (int nn = 0; nn < 5; nn++) {
            int nt = w * 5 + nn;
            h8 bf = *(const h8*)(pWx + ((size_t)((h * 40 + nt) * 3 + kb) * 64 + l) * 8);
#pragma unroll
            for (int mt = 0; mt < 5; mt++)
                acc[mt][nn] = __builtin_amdgcn_mfma_f32_16x16x32_f16(af[mt], bf, acc[mt][nn], 0, 0, 0);
        }
    }
    half_t* dst = (job ? pV : pM) + (size_t)b * 409600;
#pragma unroll
    for (int mt = 0; mt < 5; mt++) {
#pragma unroll
        for (int nn = 0; nn < 5; nn++) {
#pragma unroll
            for (int i = 0; i < 4; i++) {
                int sp = mt * 16 + aq * 4 + i;
                int c = (w * 5 + nn) * 16 + arow;
                float fv = (sp < SS) ? acc[mt][nn][i] : 0.f;
                int na, ka;
                if (job == 0) { na = h * 80 + sp; ka = c; }
                else          { ka = h * 80 + sp; na = c; }
                size_t idx = ((size_t)((na >> 4) * 20 + (ka >> 5)) * 64 +
                              ((((ka >> 3) & 3) << 4) | (na & 15))) * 8 + (ka & 7);
                dst[idx] = (half_t)fv;
            }
        }
    }
}

// swizzled LDS offset for sP: exactly 64*640 halves = 80 KiB -> allows
// full 16-wave residency. Rotation keeps frag reads at the 8-dword/bank
// conflict-free minimum (same bank map as the old +8 pad).
__device__ __forceinline__ int swz(int r, int c) {
    int t = c + r * 8;
    if (t >= 640) t -= 640;
    return r * 640 + t;
}

// =======================================================================
// K5: fused scores -> per-head register softmax -> out GEMM.
// 1024 threads = 16 waves: wm = w>>3 (32-row half), wn = w&7 (head / 80-col
// group, 5 n-tiles). acc = 40 f32/wave -> ~120 regs -> 4 waves/SIMD;
// LDS = 80 KiB exactly -> 16 waves resident (occupancy 50%).
// =======================================================================
__global__ __launch_bounds__(1024, 4) void attn_main(const float* __restrict__ hidden,
                                                     const half_t* __restrict__ pM,
                                                     const half_t* __restrict__ pV,
                                                     const float* __restrict__ bo,
                                                     float* __restrict__ out) {
    __shared__ half_t sP[64 * 640];
    int blk = blockIdx.x;
    int b = blk & 7;
    int n0 = (blk >> 3) << 6;
    int tid = threadIdx.x;
    int w = tid >> 6, l = tid & 63;
    int wm = w >> 3, wn = w & 7;
    int arow = l & 15, aq = l >> 4;
    const float* Hb = hidden + ((size_t)b * NN + n0) * CC;
    const half_t* pMb = pM + (size_t)b * 409600;
    const half_t* pVb = pV + (size_t)b * 409600;

    // ---- stage hidden 64x640 -> fp16 (swizzled), f4 loads ----
#pragma unroll
    for (int it = 0; it < 5; it++) {
        int e = (tid + it * 1024) * 8;
        int r = e / 640, c = e - r * 640;
        const float* src = Hb + (size_t)r * CC + c;
        f4 v0 = *(const f4*)src;
        f4 v1 = *(const f4*)(src + 4);
        h8 hv = {(half_t)v0[0], (half_t)v0[1], (half_t)v0[2], (half_t)v0[3],
                 (half_t)v1[0], (half_t)v1[1], (half_t)v1[2], (half_t)v1[3]};
        *(h8*)&sP[swz(r, c)] = hv;
    }
    __syncthreads();

    int rA0 = wm * 32 + arow, rA1 = rA0 + 16;
    // ---- phase A: scores = H_tile @ M_b (head wn) ----
    f4 acc[2][5];
#pragma unroll
    for (int mi = 0; mi < 2; mi++)
#pragma unroll
        for (int nt = 0; nt < 5; nt++) acc[mi][nt] = (f4){0.f, 0.f, 0.f, 0.f};
    for (int kbg = 0; kbg < 20; kbg++) {
        int ck = kbg * 32 + aq * 8;
        h8 a0 = *(const h8*)&sP[swz(rA0, ck)];
        h8 a1 = *(const h8*)&sP[swz(rA1, ck)];
#pragma unroll
        for (int nt = 0; nt < 5; nt++) {
            h8 bf = *(const h8*)(pMb + ((size_t)((wn * 5 + nt) * 20 + kbg) * 64 + l) * 8);
            acc[0][nt] = __builtin_amdgcn_mfma_f32_16x16x32_f16(a0, bf, acc[0][nt], 0, 0, 0);
            acc[1][nt] = __builtin_amdgcn_mfma_f32_16x16x32_f16(a1, bf, acc[1][nt], 0, 0, 0);
        }
    }

    // ---- per-head softmax (head = wn), fully in registers ----
    float pmax[2][4];
#pragma unroll
    for (int mi = 0; mi < 2; mi++)
#pragma unroll
        for (int i = 0; i < 4; i++) pmax[mi][i] = -1e30f;
#pragma unroll
    for (int mi = 0; mi < 2; mi++)
#pragma unroll
        for (int nt = 0; nt < 5; nt++) {
            int sl = nt * 16 + arow;
            if (sl < SS) {
#pragma unroll
                for (int i = 0; i < 4; i++)
                    pmax[mi][i] = fmaxf(pmax[mi][i], acc[mi][nt][i]);
            }
        }
#pragma unroll
    for (int st = 1; st < 16; st <<= 1)
#pragma unroll
        for (int mi = 0; mi < 2; mi++)
#pragma unroll
            for (int i = 0; i < 4; i++)
                pmax[mi][i] = fmaxf(pmax[mi][i], __shfl_xor(pmax[mi][i], st, 64));
    float psum[2][4];
#pragma unroll
    for (int mi = 0; mi < 2; mi++)
#pragma unroll
        for (int i = 0; i < 4; i++) psum[mi][i] = 0.f;
#pragma unroll
    for (int mi = 0; mi < 2; mi++)
#pragma unroll
        for (int nt = 0; nt < 5; nt++) {
            int sl = nt * 16 + arow;
            bool ok = sl < SS;
#pragma unroll
            for (int i = 0; i < 4; i++) {
                float e = ok ? __expf(acc[mi][nt][i] - pmax[mi][i]) : 0.f;
                acc[mi][nt][i] = e;
                psum[mi][i] += e;
            }
        }
#pragma unroll
    for (int st = 1; st < 16; st <<= 1)
#pragma unroll
        for (int mi = 0; mi < 2; mi++)
#pragma unroll
            for (int i = 0; i < 4; i++)
                psum[mi][i] += __shfl_xor(psum[mi][i], st, 64);
    float rinv[2][4];
#pragma unroll
    for (int mi = 0; mi < 2; mi++)
#pragma unroll
        for (int i = 0; i < 4; i++) rinv[mi][i] = 1.f / psum[mi][i];

    __syncthreads();  // all waves finished reading hidden from sP
    // ---- write P (fp16) into sP (swizzled) ----
#pragma unroll
    for (int mi = 0; mi < 2; mi++)
#pragma unroll
        for (int nt = 0; nt < 5; nt++) {
            int col = wn * 80 + nt * 16 + arow;
#pragma unroll
            for (int i = 0; i < 4; i++) {
                int r = wm * 32 + mi * 16 + aq * 4 + i;
                sP[swz(r, col)] = (half_t)(acc[mi][nt][i] * rinv[mi][i]);
            }
        }
    __syncthreads();

    // ---- phase B: out = P @ Vo_b ----
    f4 acc2[2][5];
#pragma unroll
    for (int mi = 0; mi < 2; mi++)
#pragma unroll
        for (int nt = 0; nt < 5; nt++) acc2[mi][nt] = (f4){0.f, 0.f, 0.f, 0.f};
    for (int kb = 0; kb < 20; kb++) {
        int ck = kb * 32 + aq * 8;
        h8 p0 = *(const h8*)&sP[swz(rA0, ck)];
        h8 p1 = *(const h8*)&sP[swz(rA1, ck)];
#pragma unroll
        for (int nt = 0; nt < 5; nt++) {
            h8 vf = *(const h8*)(pVb + ((size_t)((wn * 5 + nt) * 20 + kb) * 64 + l) * 8);
            acc2[0][nt] = __builtin_amdgcn_mfma_f32_16x16x32_f16(p0, vf, acc2[0][nt], 0, 0, 0);
            acc2[1][nt] = __builtin_amdgcn_mfma_f32_16x16x32_f16(p1, vf, acc2[1][nt], 0, 0, 0);
        }
    }
    float* Ob = out + ((size_t)b * NN + n0) * CC;
#pragma unroll
    for (int nt = 0; nt < 5; nt++) {
        int col = (wn * 5 + nt) * 16 + arow;
        float bias = bo[col];
#pragma unroll
        for (int mi = 0; mi < 2; mi++)
#pragma unroll
            for (int i = 0; i < 4; i++) {
                int r = wm * 32 + mi * 16 + aq * 4 + i;
                Ob[(size_t)r * CC + col] = acc2[mi][nt][i] + bias;
            }
    }
}

extern "C" void kernel_launch(void* const* d_in, const int* in_sizes, int n_in,
                              void* d_out, int out_size, void* d_ws, size_t ws_size,
                              hipStream_t stream) {
    const float* hidden = (const float*)d_in[0];
    const float* enc    = (const float*)d_in[1];
    const float* Wq     = (const float*)d_in[2];
    const float* Wk     = (const float*)d_in[3];
    const float* Wv     = (const float*)d_in[4];
    const float* Wo     = (const float*)d_in[5];
    const float* bo     = (const float*)d_in[6];
    const float* target = (const float*)d_in[7];
    const float* anchor = (const float*)d_in[8];
    const float* pres   = (const float*)d_in[9];
    float* outp = (float*)d_out;
    char* ws = (char*)d_ws;

    float* u_hat = (float*)(ws + 0);          // 77*640 f32   -> 197120
    float* wvec  = (float*)(ws + 197120);     // 77*640 f32   -> 394240
    float* ginv  = (float*)(ws + 394240);     // 77*4 f32 pad -> 395520
    float* kmat  = (float*)(ws + 395520);     // 616*640 f32  -> 1972480
    float* vmat  = (float*)(ws + 1972480);    // 616*640 f32  -> 3549440
    half_t* pW   = (half_t*)(ws + 3549440);   // 768*1280 f16 -> 5515520
    half_t* pWq  = (half_t*)(ws + 5515520);   // 8*40*3*64*8  -> 6498560
    half_t* pWo  = (half_t*)(ws + 6498560);   // 8*40*3*64*8  -> 7481600
    half_t* pM   = (half_t*)(ws + 7481600);   // 8*409600 f16 -> 14035200
    half_t* pV   = (half_t*)(ws + 14035200);  // 8*409600 f16 -> 20588800

    hipLaunchKernelGGL(wpack_all, dim3(1037), dim3(256), 0, stream, Wk, Wv, Wq, Wo,
                       target, anchor, pres, pW, pWq, pWo, u_hat, wvec, ginv);
    hipLaunchKernelGGL(kv_gemm, dim3(78), dim3(256), 0, stream, enc, pW, pres, u_hat,
                       wvec, ginv, kmat, vmat);
    hipLaunchKernelGGL(hsgemm, dim3(128), dim3(512), 0, stream, kmat, vmat, pWq, pWo, pM, pV);
    hipLaunchKernelGGL(attn_main, dim3(512), dim3(1024), 0, stream, hidden, pM, pV, bo, outp);
}